// Round 1
// baseline (67.128 us; speedup 1.0000x reference)
//
#include <hip/hip_runtime.h>
#include <hip/hip_bf16.h>
#include <math.h>

typedef float v4f __attribute__((ext_vector_type(4)));

#define PI_F 3.14159265358979323846f

// B=2, L=2048, D=256, K=32.  BL=4096.
// Chunked scan: T=32 rows per chunk, C=64 chunks per batch.

// ---------------------------------------------------------------------------
// Kernel 1: H[4096][768] = [tanh(X@kw1^T+kb1) | tanh(X@qw1^T+qb1) | X@vw^T+vb]
// Tiled fp32 GEMM: BM=BN=64, BK=32, 256 thr, 4x4 per thread.
// ---------------------------------------------------------------------------
__global__ __launch_bounds__(256) void k_gemm1(
    const float* __restrict__ X,
    const float* __restrict__ kw1, const float* __restrict__ kb1,
    const float* __restrict__ qw1, const float* __restrict__ qb1,
    const float* __restrict__ vw,  const float* __restrict__ vb,
    float* __restrict__ H)
{
    __shared__ float As[32 * 68];   // As[k][m], pad 68 (272B row: 16B-aligned, banks spread)
    __shared__ float Bs[32 * 68];   // Bs[k][n]
    const int tid = threadIdx.x;
    const int m0  = blockIdx.x * 64;
    const int by  = blockIdx.y;           // 0..11
    const int wi  = by >> 2;              // 0=kw1, 1=qw1, 2=vw
    const int nl0 = (by & 3) * 64;        // local col base within weight
    const float* W    = (wi == 0) ? kw1 : (wi == 1) ? qw1 : vw;
    const float* bias = (wi == 0) ? kb1 : (wi == 1) ? qb1 : vb;
    const int tm = tid >> 4, tn = tid & 15;

    float acc[4][4] = {};
    for (int kb = 0; kb < 256; kb += 32) {
        __syncthreads();
        #pragma unroll
        for (int it = 0; it < 2; ++it) {
            int idx = tid + it * 256;          // f4 index 0..511
            int row = idx >> 3, c4 = idx & 7;
            v4f a  = *(const v4f*)(X + (size_t)(m0  + row) * 256 + kb + c4 * 4);
            v4f bv = *(const v4f*)(W + (size_t)(nl0 + row) * 256 + kb + c4 * 4);
            #pragma unroll
            for (int j = 0; j < 4; ++j) {
                As[(c4 * 4 + j) * 68 + row] = a[j];
                Bs[(c4 * 4 + j) * 68 + row] = bv[j];
            }
        }
        __syncthreads();
        #pragma unroll
        for (int kk = 0; kk < 32; ++kk) {
            v4f a4 = *(const v4f*)&As[kk * 68 + tm * 4];
            v4f b4 = *(const v4f*)&Bs[kk * 68 + tn * 4];
            #pragma unroll
            for (int i = 0; i < 4; ++i)
                #pragma unroll
                for (int j = 0; j < 4; ++j)
                    acc[i][j] = fmaf(a4[i], b4[j], acc[i][j]);
        }
    }
    #pragma unroll
    for (int i = 0; i < 4; ++i) {
        int m   = m0 + tm * 4 + i;
        int col = nl0 + tn * 4;
        v4f v;
        #pragma unroll
        for (int j = 0; j < 4; ++j) {
            float t = acc[i][j] + bias[col + j];
            v[j] = (wi < 2) ? tanhf(t) : t;
        }
        *(v4f*)(H + (size_t)m * 768 + wi * 256 + col) = v;
    }
}

// ---------------------------------------------------------------------------
// Kernel 2: phases -> KP/QP[4096][64] = [cos(phase_0..31) | sin(phase_0..31)]
// 4 rows per block; 4 lanes cooperate per (row-out) dot.
// ---------------------------------------------------------------------------
__global__ __launch_bounds__(256) void k_encode2(
    const float* __restrict__ H,
    const float* __restrict__ kw2, const float* __restrict__ kb2,
    const float* __restrict__ qw2, const float* __restrict__ qb2,
    float* __restrict__ KP, float* __restrict__ QP)
{
    __shared__ float hrow[4][512];
    const int tid = threadIdx.x;
    const int r0  = blockIdx.x * 4;
    #pragma unroll
    for (int it = 0; it < 2; ++it) {
        int idx = tid + it * 256;          // 512 f4
        int rr = idx >> 7, j4 = idx & 127;
        *(v4f*)&hrow[rr][j4 * 4] = *(const v4f*)(H + (size_t)(r0 + rr) * 768 + j4 * 4);
    }
    __syncthreads();
    const int o = tid >> 2, p = tid & 3;   // o: 0..31 key, 32..63 query
    const int ko = (o < 32) ? o : (o - 32);
    const float* w   = ((o < 32) ? kw2 : qw2) + (size_t)ko * 256;
    const float bias = ((o < 32) ? kb2 : qb2)[ko];
    const int hoff   = (o < 32) ? 0 : 256;
    float sums[4] = {0.f, 0.f, 0.f, 0.f};
    for (int j4 = p * 16; j4 < p * 16 + 16; ++j4) {
        v4f w4 = *(const v4f*)(w + j4 * 4);
        #pragma unroll
        for (int rr = 0; rr < 4; ++rr) {
            v4f h4 = *(const v4f*)&hrow[rr][hoff + j4 * 4];
            sums[rr] += w4[0]*h4[0] + w4[1]*h4[1] + w4[2]*h4[2] + w4[3]*h4[3];
        }
    }
    #pragma unroll
    for (int rr = 0; rr < 4; ++rr) {
        sums[rr] += __shfl_xor(sums[rr], 1);
        sums[rr] += __shfl_xor(sums[rr], 2);
    }
    if (p == 0) {
        float* dst = (o < 32) ? KP : QP;
        #pragma unroll
        for (int rr = 0; rr < 4; ++rr) {
            float ph = tanhf(sums[rr] + bias) * PI_F;
            int row = r0 + rr;
            dst[(size_t)row * 64 + ko]      = cosf(ph);
            dst[(size_t)row * 64 + 32 + ko] = sinf(ph);
        }
    }
}

// ---------------------------------------------------------------------------
// Kernel 3: per-chunk state sums.  SR/SI[b][c][k][d] = sum_{t in chunk} trig*val
// grid (128, 2): x = b*64+c, y = d-half. 256 thr = (kq 8 x dq 32), 4k x 4d each.
// ---------------------------------------------------------------------------
__global__ __launch_bounds__(256) void k_chunksum(
    const float* __restrict__ H, const float* __restrict__ KP,
    float* __restrict__ SR, float* __restrict__ SI)
{
    __shared__ float KPc[32 * 68];
    __shared__ float vall[32 * 132];
    const int tid = threadIdx.x;
    const int b = blockIdx.x >> 6, c = blockIdx.x & 63;
    const int dh = blockIdx.y;
    const int row0 = b * 2048 + c * 32;
    #pragma unroll
    for (int it = 0; it < 2; ++it) {
        int idx = tid + it * 256;          // 512 f4
        int t = idx >> 4, j4 = idx & 15;
        *(v4f*)&KPc[t * 68 + j4 * 4] = *(const v4f*)(KP + (size_t)(row0 + t) * 64 + j4 * 4);
    }
    #pragma unroll
    for (int it = 0; it < 4; ++it) {
        int idx = tid + it * 256;          // 1024 f4
        int t = idx >> 5, j4 = idx & 31;
        *(v4f*)&vall[t * 132 + j4 * 4] =
            *(const v4f*)(H + (size_t)(row0 + t) * 768 + 512 + dh * 128 + j4 * 4);
    }
    __syncthreads();
    const int kq = tid >> 5, dq = tid & 31;
    float accR[4][4] = {}, accI[4][4] = {};
    for (int t = 0; t < 32; ++t) {
        v4f ck = *(const v4f*)&KPc[t * 68 + kq * 4];
        v4f sk = *(const v4f*)&KPc[t * 68 + 32 + kq * 4];
        v4f v4 = *(const v4f*)&vall[t * 132 + dq * 4];
        #pragma unroll
        for (int i = 0; i < 4; ++i)
            #pragma unroll
            for (int j = 0; j < 4; ++j) {
                accR[i][j] = fmaf(ck[i], v4[j], accR[i][j]);
                accI[i][j] = fmaf(sk[i], v4[j], accI[i][j]);
            }
    }
    #pragma unroll
    for (int i = 0; i < 4; ++i) {
        size_t base = (((size_t)(b * 64 + c)) * 32 + kq * 4 + i) * 256 + dh * 128 + dq * 4;
        v4f r, im;
        #pragma unroll
        for (int j = 0; j < 4; ++j) { r[j] = accR[i][j]; im[j] = accI[i][j]; }
        *(v4f*)(SR + base) = r;
        *(v4f*)(SI + base) = im;
    }
}

// ---------------------------------------------------------------------------
// Kernel 4: exclusive prefix over chunks, in place. One thread per (b,k,d).
// ---------------------------------------------------------------------------
__global__ __launch_bounds__(256) void k_prefix(float* __restrict__ SR, float* __restrict__ SI)
{
    int gid = blockIdx.x * 256 + threadIdx.x;   // 0..16383
    int b = gid >> 13;
    int e = gid & 8191;                         // k*256 + d
    size_t base = (size_t)b * 64 * 8192 + e;
    float runR = 0.f, runI = 0.f;
    for (int c = 0; c < 64; ++c) {
        size_t idx = base + (size_t)c * 8192;
        float r  = SR[idx]; SR[idx] = runR; runR += r;
        float im = SI[idx]; SI[idx] = runI; runI += im;
    }
}

// ---------------------------------------------------------------------------
// Kernel 5: output. grid (128, 4): x = b*64+c, y = d-quarter (64 cols).
// out[l,d] = Q . prefix_state + within-chunk causal S@V, normalized.
// ---------------------------------------------------------------------------
__global__ __launch_bounds__(256) void k_attnout(
    const float* __restrict__ H, const float* __restrict__ KP,
    const float* __restrict__ QP, const float* __restrict__ PR,
    const float* __restrict__ PIm, float* __restrict__ out)
{
    __shared__ float QPc[32 * 68], KPc[32 * 68], Sl[32 * 36];
    __shared__ float vall[32 * 68], PRl[32 * 68], PIl[32 * 68];
    const int tid = threadIdx.x;
    const int b = blockIdx.x >> 6, c = blockIdx.x & 63;
    const int dh = blockIdx.y;                 // 0..3, 64 cols each
    const int row0 = b * 2048 + c * 32;
    #pragma unroll
    for (int it = 0; it < 2; ++it) {
        int idx = tid + it * 256;              // 512 f4
        int t = idx >> 4, j4 = idx & 15;
        *(v4f*)&QPc[t * 68 + j4 * 4] = *(const v4f*)(QP + (size_t)(row0 + t) * 64 + j4 * 4);
        *(v4f*)&KPc[t * 68 + j4 * 4] = *(const v4f*)(KP + (size_t)(row0 + t) * 64 + j4 * 4);
        // 32 rows x 64 cols each = 512 f4 for these three too
        *(v4f*)&vall[t * 68 + j4 * 4] =
            *(const v4f*)(H + (size_t)(row0 + t) * 768 + 512 + dh * 64 + j4 * 4);
        size_t sb = (((size_t)(b * 64 + c)) * 32 + t) * 256 + dh * 64 + j4 * 4;  // t == k here
        *(v4f*)&PRl[t * 68 + j4 * 4] = *(const v4f*)(PR  + sb);
        *(v4f*)&PIl[t * 68 + j4 * 4] = *(const v4f*)(PIm + sb);
    }
    __syncthreads();
    // S tile (32x32, causal-masked)
    {
        const int sl = tid >> 3, tq = tid & 7;
        float s4[4] = {0.f, 0.f, 0.f, 0.f};
        for (int j4 = 0; j4 < 16; ++j4) {
            v4f q4 = *(const v4f*)&QPc[sl * 68 + j4 * 4];
            #pragma unroll
            for (int i = 0; i < 4; ++i) {
                v4f k4 = *(const v4f*)&KPc[(tq * 4 + i) * 68 + j4 * 4];
                s4[i] += q4[0]*k4[0] + q4[1]*k4[1] + q4[2]*k4[2] + q4[3]*k4[3];
            }
        }
        #pragma unroll
        for (int i = 0; i < 4; ++i) {
            int t = tq * 4 + i;
            Sl[sl * 36 + t] = (t <= sl) ? s4[i] : 0.f;
        }
    }
    __syncthreads();
    const int l = tid & 31, dq = tid >> 5;
    const int d0 = dq * 8;
    float acc[8] = {};
    for (int k = 0; k < 32; ++k) {
        float qc = QPc[l * 68 + k], qs = QPc[l * 68 + 32 + k];
        #pragma unroll
        for (int j4 = 0; j4 < 2; ++j4) {
            v4f pr = *(const v4f*)&PRl[k * 68 + d0 + j4 * 4];
            v4f pi = *(const v4f*)&PIl[k * 68 + d0 + j4 * 4];
            #pragma unroll
            for (int x = 0; x < 4; ++x)
                acc[j4 * 4 + x] += qc * pr[x] + qs * pi[x];
        }
    }
    for (int t = 0; t < 32; ++t) {
        float s = Sl[l * 36 + t];
        #pragma unroll
        for (int j4 = 0; j4 < 2; ++j4) {
            v4f v4 = *(const v4f*)&vall[t * 68 + d0 + j4 * 4];
            #pragma unroll
            for (int x = 0; x < 4; ++x)
                acc[j4 * 4 + x] = fmaf(s, v4[x], acc[j4 * 4 + x]);
        }
    }
    const int gl = c * 32 + l;
    const float inv = rsqrtf((float)((gl + 1) * 32));
    const size_t ob = ((size_t)(b * 2048 + gl)) * 256 + dh * 64 + d0;
    #pragma unroll
    for (int j4 = 0; j4 < 2; ++j4) {
        v4f v;
        #pragma unroll
        for (int x = 0; x < 4; ++x) v[x] = acc[j4 * 4 + x] * inv;
        *(v4f*)(out + ob + j4 * 4) = v;
    }
}

// ---------------------------------------------------------------------------
extern "C" void kernel_launch(void* const* d_in, const int* in_sizes, int n_in,
                              void* d_out, int out_size, void* d_ws, size_t ws_size,
                              hipStream_t stream)
{
    const float* x   = (const float*)d_in[0];
    const float* kw1 = (const float*)d_in[1];
    const float* kb1 = (const float*)d_in[2];
    const float* kw2 = (const float*)d_in[3];
    const float* kb2 = (const float*)d_in[4];
    const float* qw1 = (const float*)d_in[5];
    const float* qb1 = (const float*)d_in[6];
    const float* qw2 = (const float*)d_in[7];
    const float* qb2 = (const float*)d_in[8];
    const float* vw  = (const float*)d_in[9];
    const float* vb  = (const float*)d_in[10];
    float* out = (float*)d_out;

    float* ws = (float*)d_ws;
    float* H  = ws;                          // 4096*768
    float* QP = H  + (size_t)4096 * 768;     // 4096*64
    float* KP = QP + (size_t)4096 * 64;      // 4096*64
    float* SR = KP + (size_t)4096 * 64;      // 2*64*32*256
    float* SI = SR + (size_t)2 * 64 * 32 * 256;

    k_gemm1  <<<dim3(64, 12), 256, 0, stream>>>(x, kw1, kb1, qw1, qb1, vw, vb, H);
    k_encode2<<<1024,         256, 0, stream>>>(H, kw2, kb2, qw2, qb2, KP, QP);
    k_chunksum<<<dim3(128, 2),256, 0, stream>>>(H, KP, SR, SI);
    k_prefix <<<64,           256, 0, stream>>>(SR, SI);
    k_attnout<<<dim3(128, 4), 256, 0, stream>>>(H, KP, QP, SR, SI, out);
}

// Round 2
// 64.202 us; speedup vs baseline: 1.0456x; 1.0456x over previous
//
#include <hip/hip_runtime.h>
#include <hip/hip_bf16.h>
#include <math.h>

typedef float v4f  __attribute__((ext_vector_type(4)));
typedef float f32x4 __attribute__((ext_vector_type(4)));
typedef short s16x8 __attribute__((ext_vector_type(8)));
typedef __hip_bfloat16 bf16;

#define PI_F 3.14159265358979323846f

// B=2, L=2048, D=256, K=32.  BL=4096.  Chunks: T=32 rows, C=64 per batch.

__device__ inline unsigned short f2bf(float f) {
    unsigned int b = __float_as_uint(f);
    unsigned int r = (b + 0x7FFFu + ((b >> 16) & 1u)) >> 16;   // RNE
    return (unsigned short)r;
}
__device__ inline float bf2f(unsigned short u) {
    return __uint_as_float(((unsigned int)u) << 16);
}

// ---------------------------------------------------------------------------
// Kernel 0: fp32 -> bf16 for X (4096x256) and packed W rows [kw1|qw1|vw] (768x256)
// ---------------------------------------------------------------------------
__global__ __launch_bounds__(256) void k_tobf16(
    const float* __restrict__ X,
    const float* __restrict__ kw1, const float* __restrict__ qw1,
    const float* __restrict__ vw,
    bf16* __restrict__ Xb, bf16* __restrict__ Wb)
{
    int i4 = blockIdx.x * 256 + threadIdx.x;   // 0 .. 311295 (4864 rows * 64 v4)
    int r = i4 >> 6, c4 = i4 & 63;
    const float* src;
    bf16* dst;
    if (r < 4096) {
        src = X + (size_t)r * 256;
        dst = Xb + (size_t)r * 256;
    } else {
        int wr = r - 4096;
        src = (wr < 256) ? kw1 + (size_t)wr * 256
            : (wr < 512) ? qw1 + (size_t)(wr - 256) * 256
                         : vw  + (size_t)(wr - 512) * 256;
        dst = Wb + (size_t)wr * 256;
    }
    v4f v = *(const v4f*)(src + c4 * 4);
    ushort4 u;
    u.x = f2bf(v[0]); u.y = f2bf(v[1]); u.z = f2bf(v[2]); u.w = f2bf(v[3]);
    *(ushort4*)((unsigned short*)dst + c4 * 4) = u;
}

// ---------------------------------------------------------------------------
// Kernel 1: H[4096][768] = [tanh(X@kw1^T+kb1) | tanh(X@qw1^T+qb1) | X@vw^T+vb]
// bf16 MFMA 16x16x32. Block = 4 waves (2x2), wave tile 64x64, block tile 128x128.
// Both A and B fragments loaded with the SAME contiguous-k convention, so the
// result is exact regardless of HW k-slot permutation (layout-agnostic trick).
// ---------------------------------------------------------------------------
__global__ __launch_bounds__(256) void k_gemm1_mfma(
    const bf16* __restrict__ Xb, const bf16* __restrict__ Wb,
    const float* __restrict__ kb1, const float* __restrict__ qb1,
    const float* __restrict__ vb, float* __restrict__ H)
{
    const int tid = threadIdx.x;
    const int lane = tid & 63, wid = tid >> 6;
    const int wr = wid >> 1, wc = wid & 1;
    const int m0 = blockIdx.x * 128 + wr * 64;
    const int n0 = blockIdx.y * 128 + wc * 64;
    const int lrow = lane & 15;
    const int lk   = (lane >> 4) * 8;

    const short* A0 = (const short*)Xb + (size_t)(m0 + lrow) * 256 + lk;
    const short* B0 = (const short*)Wb + (size_t)(n0 + lrow) * 256 + lk;

    f32x4 acc[4][4] = {};
    #pragma unroll
    for (int k0 = 0; k0 < 256; k0 += 32) {
        s16x8 a[4], b[4];
        #pragma unroll
        for (int mf = 0; mf < 4; ++mf)
            a[mf] = *(const s16x8*)(A0 + mf * 16 * 256 + k0);
        #pragma unroll
        for (int nf = 0; nf < 4; ++nf)
            b[nf] = *(const s16x8*)(B0 + nf * 16 * 256 + k0);
        #pragma unroll
        for (int mf = 0; mf < 4; ++mf)
            #pragma unroll
            for (int nf = 0; nf < 4; ++nf)
                acc[mf][nf] = __builtin_amdgcn_mfma_f32_16x16x32_bf16(
                    a[mf], b[nf], acc[mf][nf], 0, 0, 0);
    }
    // Epilogue: D layout col=lane&15, row=(lane>>4)*4+reg (verified m89/m91).
    const int ocol = lane & 15;
    const int orow = (lane >> 4) * 4;
    #pragma unroll
    for (int nf = 0; nf < 4; ++nf) {
        int gcol = n0 + nf * 16 + ocol;
        float bias = (gcol < 256) ? kb1[gcol]
                   : (gcol < 512) ? qb1[gcol - 256]
                                  : vb[gcol - 512];
        bool act = gcol < 512;
        #pragma unroll
        for (int mf = 0; mf < 4; ++mf) {
            #pragma unroll
            for (int r = 0; r < 4; ++r) {
                int grow = m0 + mf * 16 + orow + r;
                float t = acc[mf][nf][r] + bias;
                H[(size_t)grow * 768 + gcol] = act ? tanhf(t) : t;
            }
        }
    }
}

// ---------------------------------------------------------------------------
// Kernel 2: phases -> KP/QP[4096][64] = [cos(phase_0..31) | sin(phase_0..31)]
// ---------------------------------------------------------------------------
__global__ __launch_bounds__(256) void k_encode2(
    const float* __restrict__ H,
    const float* __restrict__ kw2, const float* __restrict__ kb2,
    const float* __restrict__ qw2, const float* __restrict__ qb2,
    float* __restrict__ KP, float* __restrict__ QP)
{
    __shared__ float hrow[4][512];
    const int tid = threadIdx.x;
    const int r0  = blockIdx.x * 4;
    #pragma unroll
    for (int it = 0; it < 2; ++it) {
        int idx = tid + it * 256;          // 512 f4
        int rr = idx >> 7, j4 = idx & 127;
        *(v4f*)&hrow[rr][j4 * 4] = *(const v4f*)(H + (size_t)(r0 + rr) * 768 + j4 * 4);
    }
    __syncthreads();
    const int o = tid >> 2, p = tid & 3;
    const int ko = (o < 32) ? o : (o - 32);
    const float* w   = ((o < 32) ? kw2 : qw2) + (size_t)ko * 256;
    const float bias = ((o < 32) ? kb2 : qb2)[ko];
    const int hoff   = (o < 32) ? 0 : 256;
    float sums[4] = {0.f, 0.f, 0.f, 0.f};
    for (int j4 = p * 16; j4 < p * 16 + 16; ++j4) {
        v4f w4 = *(const v4f*)(w + j4 * 4);
        #pragma unroll
        for (int rr = 0; rr < 4; ++rr) {
            v4f h4 = *(const v4f*)&hrow[rr][hoff + j4 * 4];
            sums[rr] += w4[0]*h4[0] + w4[1]*h4[1] + w4[2]*h4[2] + w4[3]*h4[3];
        }
    }
    #pragma unroll
    for (int rr = 0; rr < 4; ++rr) {
        sums[rr] += __shfl_xor(sums[rr], 1);
        sums[rr] += __shfl_xor(sums[rr], 2);
    }
    if (p == 0) {
        float* dst = (o < 32) ? KP : QP;
        #pragma unroll
        for (int rr = 0; rr < 4; ++rr) {
            float ph = tanhf(sums[rr] + bias) * PI_F;
            int row = r0 + rr;
            dst[(size_t)row * 64 + ko]      = cosf(ph);
            dst[(size_t)row * 64 + 32 + ko] = sinf(ph);
        }
    }
}

// ---------------------------------------------------------------------------
// Kernel 3: per-chunk state sums -> bf16.  SR/SI[b][c][k][d]
// ---------------------------------------------------------------------------
__global__ __launch_bounds__(256) void k_chunksum(
    const float* __restrict__ H, const float* __restrict__ KP,
    bf16* __restrict__ SR, bf16* __restrict__ SI)
{
    __shared__ float KPc[32 * 68];
    __shared__ float vall[32 * 132];
    const int tid = threadIdx.x;
    const int b = blockIdx.x >> 6, c = blockIdx.x & 63;
    const int dh = blockIdx.y;
    const int row0 = b * 2048 + c * 32;
    #pragma unroll
    for (int it = 0; it < 2; ++it) {
        int idx = tid + it * 256;
        int t = idx >> 4, j4 = idx & 15;
        *(v4f*)&KPc[t * 68 + j4 * 4] = *(const v4f*)(KP + (size_t)(row0 + t) * 64 + j4 * 4);
    }
    #pragma unroll
    for (int it = 0; it < 4; ++it) {
        int idx = tid + it * 256;
        int t = idx >> 5, j4 = idx & 31;
        *(v4f*)&vall[t * 132 + j4 * 4] =
            *(const v4f*)(H + (size_t)(row0 + t) * 768 + 512 + dh * 128 + j4 * 4);
    }
    __syncthreads();
    const int kq = tid >> 5, dq = tid & 31;
    float accR[4][4] = {}, accI[4][4] = {};
    for (int t = 0; t < 32; ++t) {
        v4f ck = *(const v4f*)&KPc[t * 68 + kq * 4];
        v4f sk = *(const v4f*)&KPc[t * 68 + 32 + kq * 4];
        v4f v4 = *(const v4f*)&vall[t * 132 + dq * 4];
        #pragma unroll
        for (int i = 0; i < 4; ++i)
            #pragma unroll
            for (int j = 0; j < 4; ++j) {
                accR[i][j] = fmaf(ck[i], v4[j], accR[i][j]);
                accI[i][j] = fmaf(sk[i], v4[j], accI[i][j]);
            }
    }
    #pragma unroll
    for (int i = 0; i < 4; ++i) {
        size_t base = (((size_t)(b * 64 + c)) * 32 + kq * 4 + i) * 256 + dh * 128 + dq * 4;
        ushort4 r, im;
        r.x  = f2bf(accR[i][0]); r.y  = f2bf(accR[i][1]);
        r.z  = f2bf(accR[i][2]); r.w  = f2bf(accR[i][3]);
        im.x = f2bf(accI[i][0]); im.y = f2bf(accI[i][1]);
        im.z = f2bf(accI[i][2]); im.w = f2bf(accI[i][3]);
        *(ushort4*)((unsigned short*)SR + base) = r;
        *(ushort4*)((unsigned short*)SI + base) = im;
    }
}

// ---------------------------------------------------------------------------
// Kernel 4a: segment partial sums. 4 segments x 16 chunks. grid (128, 2) y=R/I.
// Thread handles 2 consecutive d-elements (ushort2 loads).
// PS layout: [b][seg][8192]
// ---------------------------------------------------------------------------
__global__ __launch_bounds__(256) void k_scanpart(
    bf16* __restrict__ SR, bf16* __restrict__ SI,
    float* __restrict__ PSR, float* __restrict__ PSI)
{
    const unsigned short* S = (const unsigned short*)(blockIdx.y ? SI : SR);
    float* PS = blockIdx.y ? PSI : PSR;
    int gid = blockIdx.x * 256 + threadIdx.x;     // 0..32767
    int b = gid >> 14, seg = (gid >> 12) & 3, e2 = gid & 4095;
    size_t base = ((size_t)(b * 64 + seg * 16)) * 8192 + e2 * 2;
    float s0 = 0.f, s1 = 0.f;
    #pragma unroll
    for (int c = 0; c < 16; ++c) {
        ushort2 u = *(const ushort2*)(S + base + (size_t)c * 8192);
        s0 += bf2f(u.x); s1 += bf2f(u.y);
    }
    size_t pb = ((size_t)(b * 4 + seg)) * 8192 + e2 * 2;
    PS[pb] = s0; PS[pb + 1] = s1;
}

// ---------------------------------------------------------------------------
// Kernel 4b: apply — in-place exclusive prefix within each segment + seg base.
// ---------------------------------------------------------------------------
__global__ __launch_bounds__(256) void k_scanapply(
    bf16* __restrict__ SR, bf16* __restrict__ SI,
    const float* __restrict__ PSR, const float* __restrict__ PSI)
{
    unsigned short* S = (unsigned short*)(blockIdx.y ? SI : SR);
    const float* PS = blockIdx.y ? PSI : PSR;
    int gid = blockIdx.x * 256 + threadIdx.x;
    int b = gid >> 14, seg = (gid >> 12) & 3, e2 = gid & 4095;
    size_t base = ((size_t)(b * 64 + seg * 16)) * 8192 + e2 * 2;
    float r0 = 0.f, r1 = 0.f;
    for (int s = 0; s < seg; ++s) {
        size_t pb = ((size_t)(b * 4 + s)) * 8192 + e2 * 2;
        r0 += PS[pb]; r1 += PS[pb + 1];
    }
    for (int c = 0; c < 16; ++c) {
        size_t idx = base + (size_t)c * 8192;
        ushort2 u = *(const ushort2*)(S + idx);
        ushort2 w; w.x = f2bf(r0); w.y = f2bf(r1);
        *(ushort2*)(S + idx) = w;
        r0 += bf2f(u.x); r1 += bf2f(u.y);
    }
}

// ---------------------------------------------------------------------------
// Kernel 5: output. grid (128, 4): x = b*64+c, y = d-quarter (64 cols).
// ---------------------------------------------------------------------------
__global__ __launch_bounds__(256) void k_attnout(
    const float* __restrict__ H, const float* __restrict__ KP,
    const float* __restrict__ QP, const bf16* __restrict__ PR,
    const bf16* __restrict__ PIm, float* __restrict__ out)
{
    __shared__ float QPc[32 * 68], KPc[32 * 68], Sl[32 * 36];
    __shared__ float vall[32 * 68], PRl[32 * 68], PIl[32 * 68];
    const int tid = threadIdx.x;
    const int b = blockIdx.x >> 6, c = blockIdx.x & 63;
    const int dh = blockIdx.y;
    const int row0 = b * 2048 + c * 32;
    #pragma unroll
    for (int it = 0; it < 2; ++it) {
        int idx = tid + it * 256;
        int t = idx >> 4, j4 = idx & 15;
        *(v4f*)&QPc[t * 68 + j4 * 4] = *(const v4f*)(QP + (size_t)(row0 + t) * 64 + j4 * 4);
        *(v4f*)&KPc[t * 68 + j4 * 4] = *(const v4f*)(KP + (size_t)(row0 + t) * 64 + j4 * 4);
        *(v4f*)&vall[t * 68 + j4 * 4] =
            *(const v4f*)(H + (size_t)(row0 + t) * 768 + 512 + dh * 64 + j4 * 4);
        size_t sb = (((size_t)(b * 64 + c)) * 32 + t) * 256 + dh * 64 + j4 * 4;
        ushort4 ur = *(const ushort4*)((const unsigned short*)PR  + sb);
        ushort4 ui = *(const ushort4*)((const unsigned short*)PIm + sb);
        PRl[t * 68 + j4 * 4 + 0] = bf2f(ur.x);
        PRl[t * 68 + j4 * 4 + 1] = bf2f(ur.y);
        PRl[t * 68 + j4 * 4 + 2] = bf2f(ur.z);
        PRl[t * 68 + j4 * 4 + 3] = bf2f(ur.w);
        PIl[t * 68 + j4 * 4 + 0] = bf2f(ui.x);
        PIl[t * 68 + j4 * 4 + 1] = bf2f(ui.y);
        PIl[t * 68 + j4 * 4 + 2] = bf2f(ui.z);
        PIl[t * 68 + j4 * 4 + 3] = bf2f(ui.w);
    }
    __syncthreads();
    {
        const int sl = tid >> 3, tq = tid & 7;
        float s4[4] = {0.f, 0.f, 0.f, 0.f};
        for (int j4 = 0; j4 < 16; ++j4) {
            v4f q4 = *(const v4f*)&QPc[sl * 68 + j4 * 4];
            #pragma unroll
            for (int i = 0; i < 4; ++i) {
                v4f k4 = *(const v4f*)&KPc[(tq * 4 + i) * 68 + j4 * 4];
                s4[i] += q4[0]*k4[0] + q4[1]*k4[1] + q4[2]*k4[2] + q4[3]*k4[3];
            }
        }
        #pragma unroll
        for (int i = 0; i < 4; ++i) {
            int t = tq * 4 + i;
            Sl[sl * 36 + t] = (t <= sl) ? s4[i] : 0.f;
        }
    }
    __syncthreads();
    const int l = tid & 31, dq = tid >> 5;
    const int d0 = dq * 8;
    float acc[8] = {};
    for (int k = 0; k < 32; ++k) {
        float qc = QPc[l * 68 + k], qs = QPc[l * 68 + 32 + k];
        #pragma unroll
        for (int j4 = 0; j4 < 2; ++j4) {
            v4f pr = *(const v4f*)&PRl[k * 68 + d0 + j4 * 4];
            v4f pi = *(const v4f*)&PIl[k * 68 + d0 + j4 * 4];
            #pragma unroll
            for (int x = 0; x < 4; ++x)
                acc[j4 * 4 + x] += qc * pr[x] + qs * pi[x];
        }
    }
    for (int t = 0; t < 32; ++t) {
        float s = Sl[l * 36 + t];
        #pragma unroll
        for (int j4 = 0; j4 < 2; ++j4) {
            v4f v4 = *(const v4f*)&vall[t * 68 + d0 + j4 * 4];
            #pragma unroll
            for (int x = 0; x < 4; ++x)
                acc[j4 * 4 + x] = fmaf(s, v4[x], acc[j4 * 4 + x]);
        }
    }
    const int gl = c * 32 + l;
    const float inv = rsqrtf((float)((gl + 1) * 32));
    const size_t ob = ((size_t)(b * 2048 + gl)) * 256 + dh * 64 + d0;
    #pragma unroll
    for (int j4 = 0; j4 < 2; ++j4) {
        v4f v;
        #pragma unroll
        for (int x = 0; x < 4; ++x) v[x] = acc[j4 * 4 + x] * inv;
        *(v4f*)(out + ob + j4 * 4) = v;
    }
}

// ---------------------------------------------------------------------------
extern "C" void kernel_launch(void* const* d_in, const int* in_sizes, int n_in,
                              void* d_out, int out_size, void* d_ws, size_t ws_size,
                              hipStream_t stream)
{
    const float* x   = (const float*)d_in[0];
    const float* kw1 = (const float*)d_in[1];
    const float* kb1 = (const float*)d_in[2];
    const float* kw2 = (const float*)d_in[3];
    const float* kb2 = (const float*)d_in[4];
    const float* qw1 = (const float*)d_in[5];
    const float* qb1 = (const float*)d_in[6];
    const float* qw2 = (const float*)d_in[7];
    const float* qb2 = (const float*)d_in[8];
    const float* vw  = (const float*)d_in[9];
    const float* vb  = (const float*)d_in[10];
    float* out = (float*)d_out;

    char* ws = (char*)d_ws;
    float* H   = (float*)ws;                          ws += (size_t)4096 * 768 * 4;
    float* QP  = (float*)ws;                          ws += (size_t)4096 * 64 * 4;
    float* KP  = (float*)ws;                          ws += (size_t)4096 * 64 * 4;
    float* PSR = (float*)ws;                          ws += (size_t)65536 * 4;
    float* PSI = (float*)ws;                          ws += (size_t)65536 * 4;
    bf16*  Xb  = (bf16*)ws;                           ws += (size_t)4096 * 256 * 2;
    bf16*  Wb  = (bf16*)ws;                           ws += (size_t)768 * 256 * 2;
    bf16*  SR  = (bf16*)ws;                           ws += (size_t)2 * 64 * 32 * 256 * 2;
    bf16*  SI  = (bf16*)ws;                           ws += (size_t)2 * 64 * 32 * 256 * 2;

    k_tobf16    <<<1216,          256, 0, stream>>>(x, kw1, qw1, vw, Xb, Wb);
    k_gemm1_mfma<<<dim3(32, 6),   256, 0, stream>>>(Xb, Wb, kb1, qb1, vb, H);
    k_encode2   <<<1024,          256, 0, stream>>>(H, kw2, kb2, qw2, qb2, KP, QP);
    k_chunksum  <<<dim3(128, 2),  256, 0, stream>>>(H, KP, SR, SI);
    k_scanpart  <<<dim3(128, 2),  256, 0, stream>>>(SR, SI, PSR, PSI);
    k_scanapply <<<dim3(128, 2),  256, 0, stream>>>(SR, SI, PSR, PSI);
    k_attnout   <<<dim3(128, 4),  256, 0, stream>>>(H, KP, QP, SR, SI, out);
}

// Round 3
// 51.754 us; speedup vs baseline: 1.2971x; 1.2405x over previous
//
#include <hip/hip_runtime.h>
#include <hip/hip_bf16.h>
#include <math.h>

typedef float v4f   __attribute__((ext_vector_type(4)));
typedef float f32x4 __attribute__((ext_vector_type(4)));
typedef short s16x8 __attribute__((ext_vector_type(8)));
typedef __hip_bfloat16 bf16;

#define PI_F 3.14159265358979323846f

// B=2, L=2048, D=256, K=32. BL=4096. Chunks: T=32 rows, 64/batch, 128 total.

__device__ inline unsigned short f2bf(float f) {
    unsigned int b = __float_as_uint(f);
    unsigned int r = (b + 0x7FFFu + ((b >> 16) & 1u)) >> 16;   // RNE
    return (unsigned short)r;
}
__device__ inline float bf2f(unsigned short u) {
    return __uint_as_float(((unsigned int)u) << 16);
}
__device__ inline void cvt8(const float* __restrict__ src, unsigned short* dst) {
    v4f a = *(const v4f*)src, b = *(const v4f*)(src + 4);
    ushort4 u0, u1;
    u0.x = f2bf(a[0]); u0.y = f2bf(a[1]); u0.z = f2bf(a[2]); u0.w = f2bf(a[3]);
    u1.x = f2bf(b[0]); u1.y = f2bf(b[1]); u1.z = f2bf(b[2]); u1.w = f2bf(b[3]);
    *(ushort4*)dst = u0; *(ushort4*)(dst + 4) = u1;
}

// ---------------------------------------------------------------------------
// Kernel A: one-time weight conversion.
// Wb[768][256] = [kw1|qw1|vw] bf16 ; W2b[64][256] = [kw2|qw2] bf16.
// 832 rows * 32 groups-of-8 = 26624 threads -> 104 blocks.
// ---------------------------------------------------------------------------
__global__ __launch_bounds__(256) void k_cvtw(
    const float* __restrict__ kw1, const float* __restrict__ qw1,
    const float* __restrict__ vw,  const float* __restrict__ kw2,
    const float* __restrict__ qw2, bf16* __restrict__ Wb, bf16* __restrict__ W2b)
{
    int i8 = blockIdx.x * 256 + threadIdx.x;
    int r = i8 >> 5, c8 = (i8 & 31) * 8;
    const float* src;
    unsigned short* dst;
    if (r < 768) {
        src = (r < 256) ? kw1 + (size_t)r * 256
            : (r < 512) ? qw1 + (size_t)(r - 256) * 256
                        : vw  + (size_t)(r - 512) * 256;
        dst = (unsigned short*)Wb + (size_t)r * 256;
    } else {
        int r2 = r - 768;
        src = (r2 < 32) ? kw2 + (size_t)r2 * 256 : qw2 + (size_t)(r2 - 32) * 256;
        dst = (unsigned short*)W2b + (size_t)r2 * 256;
    }
    cvt8(src + c8, dst + c8);
}

// ---------------------------------------------------------------------------
// Kernel B: fused encode + chunk-state. One block per (b, chunk): 128 blocks,
// 1024 threads (16 waves). LDS 58.9 KB (Abf region reused for Vt/CK).
//   1) X tile -> bf16 LDS
//   2) GEMM1: H(32x768) = X @ [kw1|qw1|vw]^T  (MFMA, acc in regs)
//   3) epilogue: Hkq bf16 LDS (tanh'd), Vt (transposed) LDS + Vb global
//   4) GEMM2: phases(32x32 x2) = Hkq @ w2^T -> tanh*pi -> sincos
//             -> KP/QP global, CKc/CKs (transposed cos/sin of K) LDS
//   5) GEMM3: SR/SI(32k x 256d) = CK^T @ V  (one MFMA step, K=32)
// ---------------------------------------------------------------------------
__global__ __launch_bounds__(1024) void k_fused1(
    const float* __restrict__ X,   const bf16* __restrict__ Wbk,
    const float* __restrict__ kb1, const float* __restrict__ qb1,
    const float* __restrict__ vb,  const bf16* __restrict__ W2bk,
    const float* __restrict__ kb2, const float* __restrict__ qb2,
    float* __restrict__ KP, float* __restrict__ QP,
    bf16* __restrict__ Vb, bf16* __restrict__ SRg, bf16* __restrict__ SIg)
{
    __shared__ __align__(16) unsigned char smem[58880];
    unsigned short* Abf = (unsigned short*)smem;            // 32x264 bf16 = 16896 B
    unsigned short* Vt  = (unsigned short*)smem;            // 256x40 bf16 = 20480 B (after GEMM1)
    unsigned short* CKc = (unsigned short*)(smem + 20480);  // 32x40 = 2560 B
    unsigned short* CKs = (unsigned short*)(smem + 23040);  // 32x40 = 2560 B
    unsigned short* Hkq = (unsigned short*)(smem + 25600);  // 32x520 bf16 = 33280 B

    const int tid  = threadIdx.x;
    const int lane = tid & 63, wid = tid >> 6;          // 16 waves
    const int lrow = lane & 15, lk8 = (lane >> 4) * 8;
    const int t0   = (lane >> 4) * 4;
    const int bb = blockIdx.x >> 6, cc = blockIdx.x & 63;
    const int row0 = bb * 2048 + cc * 32;

    // ---- 1) stage X tile (fp32 -> bf16 LDS) ----
    {
        int r = tid >> 5, c8 = (tid & 31) * 8;
        cvt8(X + (size_t)(row0 + r) * 256 + c8, &Abf[r * 264 + c8]);
    }
    __syncthreads();

    // ---- 2) GEMM1: wave owns cols nb..nb+47 (3 n-frags x 2 m-frags) ----
    const int nb = wid * 48;
    const unsigned short* Wu = (const unsigned short*)Wbk;
    f32x4 acc[2][3] = {};
    for (int k0 = 0; k0 < 256; k0 += 32) {
        s16x8 a[2], b[3];
        #pragma unroll
        for (int mf = 0; mf < 2; ++mf)
            a[mf] = *(const s16x8*)&Abf[(mf * 16 + lrow) * 264 + k0 + lk8];
        #pragma unroll
        for (int nf = 0; nf < 3; ++nf)
            b[nf] = *(const s16x8*)(Wu + (size_t)(nb + nf * 16 + lrow) * 256 + k0 + lk8);
        #pragma unroll
        for (int mf = 0; mf < 2; ++mf)
            #pragma unroll
            for (int nf = 0; nf < 3; ++nf)
                acc[mf][nf] = __builtin_amdgcn_mfma_f32_16x16x32_bf16(
                    a[mf], b[nf], acc[mf][nf], 0, 0, 0);
    }
    __syncthreads();   // all A reads done before Abf region is reused as Vt

    // ---- 3) epilogue -> Hkq / Vt LDS (+ Vb global) ----
    #pragma unroll
    for (int nf = 0; nf < 3; ++nf) {
        int n = nb + nf * 16 + lrow;
        float bias = (n < 256) ? kb1[n] : (n < 512) ? qb1[n - 256] : vb[n - 512];
        #pragma unroll
        for (int mf = 0; mf < 2; ++mf) {
            int tb = mf * 16 + t0;
            if (n < 512) {
                #pragma unroll
                for (int r = 0; r < 4; ++r)
                    Hkq[(tb + r) * 520 + n] = f2bf(tanhf(acc[mf][nf][r] + bias));
            } else {
                int d = n - 512;
                float v0 = acc[mf][nf][0] + bias, v1 = acc[mf][nf][1] + bias;
                float v2 = acc[mf][nf][2] + bias, v3 = acc[mf][nf][3] + bias;
                ushort4 u;
                u.x = f2bf(v0); u.y = f2bf(v1); u.z = f2bf(v2); u.w = f2bf(v3);
                *(ushort4*)&Vt[d * 40 + tb] = u;
                unsigned short* Vg = (unsigned short*)Vb + (size_t)(row0 + tb) * 256 + d;
                Vg[0] = u.x; Vg[256] = u.y; Vg[512] = u.z; Vg[768] = u.w;
            }
        }
    }
    __syncthreads();

    // ---- 4) GEMM2 (waves 0-7): layer-2 + trig ----
    if (wid < 8) {
        const int which = wid >> 2;           // 0=K, 1=Q
        const int q = wid & 3, mf = q >> 1, nf = q & 1;
        const int hoff = which * 256;
        const unsigned short* W2u =
            (const unsigned short*)W2bk + (size_t)(which * 32 + nf * 16 + lrow) * 256;
        f32x4 u = {};
        for (int k0 = 0; k0 < 256; k0 += 32) {
            s16x8 a = *(const s16x8*)&Hkq[(mf * 16 + lrow) * 520 + hoff + k0 + lk8];
            s16x8 b = *(const s16x8*)(W2u + k0 + lk8);
            u = __builtin_amdgcn_mfma_f32_16x16x32_bf16(a, b, u, 0, 0, 0);
        }
        const int outk = nf * 16 + lrow;      // phase index 0..31
        const float bias = (which ? qb2 : kb2)[outk];
        float* dst = which ? QP : KP;
        float cs[4], sn[4];
        #pragma unroll
        for (int r = 0; r < 4; ++r) {
            float ph = tanhf(u[r] + bias) * PI_F;
            float s, c_;
            __sincosf(ph, &s, &c_);
            cs[r] = c_; sn[r] = s;
            int row = mf * 16 + t0 + r;
            dst[(size_t)(row0 + row) * 64 + outk]      = c_;
            dst[(size_t)(row0 + row) * 64 + 32 + outk] = s;
        }
        if (which == 0) {
            ushort4 uc, us;
            uc.x = f2bf(cs[0]); uc.y = f2bf(cs[1]); uc.z = f2bf(cs[2]); uc.w = f2bf(cs[3]);
            us.x = f2bf(sn[0]); us.y = f2bf(sn[1]); us.z = f2bf(sn[2]); us.w = f2bf(sn[3]);
            *(ushort4*)&CKc[outk * 40 + mf * 16 + t0] = uc;
            *(ushort4*)&CKs[outk * 40 + mf * 16 + t0] = us;
        }
    }
    __syncthreads();

    // ---- 5) GEMM3: chunk sums. wave wid owns d-block wid*16..+15 ----
    {
        s16x8 bV = *(const s16x8*)&Vt[(wid * 16 + lrow) * 40 + lk8];
        s16x8 c0 = *(const s16x8*)&CKc[(lrow) * 40 + lk8];
        s16x8 c1 = *(const s16x8*)&CKc[(16 + lrow) * 40 + lk8];
        s16x8 s0 = *(const s16x8*)&CKs[(lrow) * 40 + lk8];
        s16x8 s1 = *(const s16x8*)&CKs[(16 + lrow) * 40 + lk8];
        f32x4 z = {};
        f32x4 r0 = __builtin_amdgcn_mfma_f32_16x16x32_bf16(c0, bV, z, 0, 0, 0);
        f32x4 r1 = __builtin_amdgcn_mfma_f32_16x16x32_bf16(c1, bV, z, 0, 0, 0);
        f32x4 i0 = __builtin_amdgcn_mfma_f32_16x16x32_bf16(s0, bV, z, 0, 0, 0);
        f32x4 i1 = __builtin_amdgcn_mfma_f32_16x16x32_bf16(s1, bV, z, 0, 0, 0);
        const int d = wid * 16 + lrow;
        size_t base = (((size_t)(bb * 64 + cc)) * 32) * 256 + d;
        unsigned short* SRu = (unsigned short*)SRg;
        unsigned short* SIu = (unsigned short*)SIg;
        #pragma unroll
        for (int r = 0; r < 4; ++r) {
            int ka = t0 + r, kb_ = 16 + t0 + r;
            SRu[base + (size_t)ka  * 256] = f2bf(r0[r]);
            SRu[base + (size_t)kb_ * 256] = f2bf(r1[r]);
            SIu[base + (size_t)ka  * 256] = f2bf(i0[r]);
            SIu[base + (size_t)kb_ * 256] = f2bf(i1[r]);
        }
    }
}

// ---------------------------------------------------------------------------
// Kernel C: segment partial sums (4 segs x 16 chunks). grid (128, 2) y=R/I.
// PS layout: [b][seg][8192] fp32.
// ---------------------------------------------------------------------------
__global__ __launch_bounds__(256) void k_scanpart(
    const bf16* __restrict__ SRg, const bf16* __restrict__ SIg,
    float* __restrict__ PSR, float* __restrict__ PSI)
{
    const unsigned short* S = (const unsigned short*)(blockIdx.y ? SIg : SRg);
    float* PS = blockIdx.y ? PSI : PSR;
    int gid = blockIdx.x * 256 + threadIdx.x;     // 0..32767
    int b = gid >> 14, seg = (gid >> 12) & 3, e2 = gid & 4095;
    size_t base = ((size_t)(b * 64 + seg * 16)) * 8192 + e2 * 2;
    float s0 = 0.f, s1 = 0.f;
    #pragma unroll
    for (int c = 0; c < 16; ++c) {
        ushort2 u = *(const ushort2*)(S + base + (size_t)c * 8192);
        s0 += bf2f(u.x); s1 += bf2f(u.y);
    }
    size_t pb = ((size_t)(b * 4 + seg)) * 8192 + e2 * 2;
    PS[pb] = s0; PS[pb + 1] = s1;
}

// ---------------------------------------------------------------------------
// Kernel D: output. grid (128, 4): x = b*64+c, y = d-quarter (64 cols).
// Prefix state rebuilt inline: sum of prior segment PS tiles (fp32) + prior
// chunk-sum tiles within segment (bf16).
// ---------------------------------------------------------------------------
__global__ __launch_bounds__(256) void k_attnout(
    const float* __restrict__ KP, const float* __restrict__ QP,
    const bf16* __restrict__ Vb,
    const bf16* __restrict__ SRg, const bf16* __restrict__ SIg,
    const float* __restrict__ PSR, const float* __restrict__ PSI,
    float* __restrict__ out)
{
    __shared__ float QPc[32 * 68], KPc[32 * 68], Sl[32 * 36];
    __shared__ float vall[32 * 68], PRl[32 * 68], PIl[32 * 68];
    const int tid = threadIdx.x;
    const int b = blockIdx.x >> 6, c = blockIdx.x & 63;
    const int dh = blockIdx.y;
    const int row0 = b * 2048 + c * 32;

    #pragma unroll
    for (int it = 0; it < 2; ++it) {
        int idx = tid + it * 256, t = idx >> 4, j4 = idx & 15;
        *(v4f*)&QPc[t * 68 + j4 * 4] = *(const v4f*)(QP + (size_t)(row0 + t) * 64 + j4 * 4);
        *(v4f*)&KPc[t * 68 + j4 * 4] = *(const v4f*)(KP + (size_t)(row0 + t) * 64 + j4 * 4);
    }
    {   // V slice bf16 -> LDS fp32
        int t = tid >> 3, e8 = (tid & 7) * 8;
        s16x8 u = *(const s16x8*)((const unsigned short*)Vb
                                  + (size_t)(row0 + t) * 256 + dh * 64 + e8);
        #pragma unroll
        for (int j = 0; j < 8; ++j) vall[t * 68 + e8 + j] = bf2f((unsigned short)u[j]);
    }
    {   // inline exclusive-prefix reconstruction
        int k = tid >> 3, dg = tid & 7;
        float pr[8] = {}, pi[8] = {};
        int seg = c >> 4;
        for (int s = 0; s < seg; ++s) {
            size_t pb = ((size_t)(b * 4 + s)) * 8192 + k * 256 + dh * 64 + dg * 8;
            v4f r0 = *(const v4f*)(PSR + pb), r1 = *(const v4f*)(PSR + pb + 4);
            v4f i0 = *(const v4f*)(PSI + pb), i1 = *(const v4f*)(PSI + pb + 4);
            #pragma unroll
            for (int j = 0; j < 4; ++j) {
                pr[j] += r0[j]; pr[4 + j] += r1[j];
                pi[j] += i0[j]; pi[4 + j] += i1[j];
            }
        }
        for (int cp = (seg << 4); cp < c; ++cp) {
            size_t sb = (((size_t)(b * 64 + cp)) * 32 + k) * 256 + dh * 64 + dg * 8;
            s16x8 ur = *(const s16x8*)((const unsigned short*)SRg + sb);
            s16x8 ui = *(const s16x8*)((const unsigned short*)SIg + sb);
            #pragma unroll
            for (int j = 0; j < 8; ++j) {
                pr[j] += bf2f((unsigned short)ur[j]);
                pi[j] += bf2f((unsigned short)ui[j]);
            }
        }
        #pragma unroll
        for (int j = 0; j < 8; ++j) {
            PRl[k * 68 + dg * 8 + j] = pr[j];
            PIl[k * 68 + dg * 8 + j] = pi[j];
        }
    }
    __syncthreads();
    {   // S tile (32x32, causal-masked)
        const int sl = tid >> 3, tq = tid & 7;
        float s4[4] = {0.f, 0.f, 0.f, 0.f};
        for (int j4 = 0; j4 < 16; ++j4) {
            v4f q4 = *(const v4f*)&QPc[sl * 68 + j4 * 4];
            #pragma unroll
            for (int i = 0; i < 4; ++i) {
                v4f k4 = *(const v4f*)&KPc[(tq * 4 + i) * 68 + j4 * 4];
                s4[i] += q4[0]*k4[0] + q4[1]*k4[1] + q4[2]*k4[2] + q4[3]*k4[3];
            }
        }
        #pragma unroll
        for (int i = 0; i < 4; ++i) {
            int t = tq * 4 + i;
            Sl[sl * 36 + t] = (t <= sl) ? s4[i] : 0.f;
        }
    }
    __syncthreads();
    const int l = tid & 31, dq = tid >> 5;
    const int d0 = dq * 8;
    float acc[8] = {};
    for (int k = 0; k < 32; ++k) {
        float qc = QPc[l * 68 + k], qs = QPc[l * 68 + 32 + k];
        #pragma unroll
        for (int j4 = 0; j4 < 2; ++j4) {
            v4f pr = *(const v4f*)&PRl[k * 68 + d0 + j4 * 4];
            v4f pi = *(const v4f*)&PIl[k * 68 + d0 + j4 * 4];
            #pragma unroll
            for (int x = 0; x < 4; ++x)
                acc[j4 * 4 + x] += qc * pr[x] + qs * pi[x];
        }
    }
    for (int t = 0; t < 32; ++t) {
        float s = Sl[l * 36 + t];
        #pragma unroll
        for (int j4 = 0; j4 < 2; ++j4) {
            v4f v4 = *(const v4f*)&vall[t * 68 + d0 + j4 * 4];
            #pragma unroll
            for (int x = 0; x < 4; ++x)
                acc[j4 * 4 + x] = fmaf(s, v4[x], acc[j4 * 4 + x]);
        }
    }
    const int gl = c * 32 + l;
    const float inv = rsqrtf((float)((gl + 1) * 32));
    const size_t ob = ((size_t)(b * 2048 + gl)) * 256 + dh * 64 + d0;
    #pragma unroll
    for (int j4 = 0; j4 < 2; ++j4) {
        v4f v;
        #pragma unroll
        for (int x = 0; x < 4; ++x) v[x] = acc[j4 * 4 + x] * inv;
        *(v4f*)(out + ob + j4 * 4) = v;
    }
}

// ---------------------------------------------------------------------------
extern "C" void kernel_launch(void* const* d_in, const int* in_sizes, int n_in,
                              void* d_out, int out_size, void* d_ws, size_t ws_size,
                              hipStream_t stream)
{
    const float* x   = (const float*)d_in[0];
    const float* kw1 = (const float*)d_in[1];
    const float* kb1 = (const float*)d_in[2];
    const float* kw2 = (const float*)d_in[3];
    const float* kb2 = (const float*)d_in[4];
    const float* qw1 = (const float*)d_in[5];
    const float* qb1 = (const float*)d_in[6];
    const float* qw2 = (const float*)d_in[7];
    const float* qb2 = (const float*)d_in[8];
    const float* vw  = (const float*)d_in[9];
    const float* vb  = (const float*)d_in[10];
    float* out = (float*)d_out;

    char* ws = (char*)d_ws;
    float* KP  = (float*)ws;   ws += (size_t)4096 * 64 * 4;
    float* QP  = (float*)ws;   ws += (size_t)4096 * 64 * 4;
    float* PSR = (float*)ws;   ws += (size_t)65536 * 4;
    float* PSI = (float*)ws;   ws += (size_t)65536 * 4;
    bf16*  Wb  = (bf16*)ws;    ws += (size_t)768 * 256 * 2;
    bf16*  W2b = (bf16*)ws;    ws += (size_t)64 * 256 * 2;
    bf16*  Vb  = (bf16*)ws;    ws += (size_t)4096 * 256 * 2;
    bf16*  SR  = (bf16*)ws;    ws += (size_t)2 * 64 * 32 * 256 * 2;
    bf16*  SI  = (bf16*)ws;    ws += (size_t)2 * 64 * 32 * 256 * 2;

    k_cvtw    <<<104,          256,  0, stream>>>(kw1, qw1, vw, kw2, qw2, Wb, W2b);
    k_fused1  <<<128,          1024, 0, stream>>>(x, Wb, kb1, qb1, vb, W2b, kb2, qb2,
                                                  KP, QP, Vb, SR, SI);
    k_scanpart<<<dim3(128, 2), 256,  0, stream>>>(SR, SI, PSR, PSI);
    k_attnout <<<dim3(128, 4), 256,  0, stream>>>(KP, QP, Vb, SR, SI, PSR, PSI, out);
}

// Round 4
// 51.725 us; speedup vs baseline: 1.2978x; 1.0006x over previous
//
#include <hip/hip_runtime.h>
#include <hip/hip_bf16.h>
#include <math.h>

typedef float v4f   __attribute__((ext_vector_type(4)));
typedef float f32x4 __attribute__((ext_vector_type(4)));
typedef short s16x8 __attribute__((ext_vector_type(8)));
typedef __hip_bfloat16 bf16;

#define PI_F 3.14159265358979323846f

// B=2, L=2048, D=256, K=32. BL=4096. Chunks: T=32 rows, 64/batch, 128 total.

__device__ inline unsigned short f2bf(float f) {
    unsigned int b = __float_as_uint(f);
    unsigned int r = (b + 0x7FFFu + ((b >> 16) & 1u)) >> 16;   // RNE
    return (unsigned short)r;
}
__device__ inline float bf2f(unsigned short u) {
    return __uint_as_float(((unsigned int)u) << 16);
}
__device__ inline void cvt8(const float* __restrict__ src, unsigned short* dst) {
    v4f a = *(const v4f*)src, b = *(const v4f*)(src + 4);
    ushort4 u0, u1;
    u0.x = f2bf(a[0]); u0.y = f2bf(a[1]); u0.z = f2bf(a[2]); u0.w = f2bf(a[3]);
    u1.x = f2bf(b[0]); u1.y = f2bf(b[1]); u1.z = f2bf(b[2]); u1.w = f2bf(b[3]);
    *(ushort4*)dst = u0; *(ushort4*)(dst + 4) = u1;
}

// ---------------------------------------------------------------------------
// Kernel A: one-time weight conversion.
// Wb[768][256] = [kw1|qw1|vw] bf16 ; W2b[64][256] = [kw2|qw2] bf16.
// 832 rows * 32 groups-of-8 = 26624 threads -> 104 blocks.
// ---------------------------------------------------------------------------
__global__ __launch_bounds__(256) void k_cvtw(
    const float* __restrict__ kw1, const float* __restrict__ qw1,
    const float* __restrict__ vw,  const float* __restrict__ kw2,
    const float* __restrict__ qw2, bf16* __restrict__ Wb, bf16* __restrict__ W2b)
{
    int i8 = blockIdx.x * 256 + threadIdx.x;
    int r = i8 >> 5, c8 = (i8 & 31) * 8;
    const float* src;
    unsigned short* dst;
    if (r < 768) {
        src = (r < 256) ? kw1 + (size_t)r * 256
            : (r < 512) ? qw1 + (size_t)(r - 256) * 256
                        : vw  + (size_t)(r - 512) * 256;
        dst = (unsigned short*)Wb + (size_t)r * 256;
    } else {
        int r2 = r - 768;
        src = (r2 < 32) ? kw2 + (size_t)r2 * 256 : qw2 + (size_t)(r2 - 32) * 256;
        dst = (unsigned short*)W2b + (size_t)r2 * 256;
    }
    cvt8(src + c8, dst + c8);
}

// ---------------------------------------------------------------------------
// Kernel B: fused encode + chunk-state. One block per (b, chunk): 128 blocks,
// 1024 threads (16 waves). LDS 58.9 KB (Abf region reused for Vt/CK).
//   1) X tile -> bf16 LDS
//   2) GEMM1: H(32x768) = X @ [kw1|qw1|vw]^T  (MFMA, acc in regs)
//   3) epilogue: Hkq bf16 LDS (tanh'd), Vt (transposed) LDS + Vb global
//   4) GEMM2: phases(32x32 x2) = Hkq @ w2^T -> tanh*pi -> sincos
//             -> KP/QP global, CKc/CKs (transposed cos/sin of K) LDS
//   5) GEMM3: SR/SI(32k x 256d) = CK^T @ V  (one MFMA step, K=32)
// ---------------------------------------------------------------------------
__global__ __launch_bounds__(1024) void k_fused1(
    const float* __restrict__ X,   const bf16* __restrict__ Wbk,
    const float* __restrict__ kb1, const float* __restrict__ qb1,
    const float* __restrict__ vb,  const bf16* __restrict__ W2bk,
    const float* __restrict__ kb2, const float* __restrict__ qb2,
    float* __restrict__ KP, float* __restrict__ QP,
    bf16* __restrict__ Vb, bf16* __restrict__ SRg, bf16* __restrict__ SIg)
{
    __shared__ __align__(16) unsigned char smem[58880];
    unsigned short* Abf = (unsigned short*)smem;            // 32x264 bf16 = 16896 B
    unsigned short* Vt  = (unsigned short*)smem;            // 256x40 bf16 = 20480 B (after GEMM1)
    unsigned short* CKc = (unsigned short*)(smem + 20480);  // 32x40 = 2560 B
    unsigned short* CKs = (unsigned short*)(smem + 23040);  // 32x40 = 2560 B
    unsigned short* Hkq = (unsigned short*)(smem + 25600);  // 32x520 bf16 = 33280 B

    const int tid  = threadIdx.x;
    const int lane = tid & 63, wid = tid >> 6;          // 16 waves
    const int lrow = lane & 15, lk8 = (lane >> 4) * 8;
    const int t0   = (lane >> 4) * 4;
    const int bb = blockIdx.x >> 6, cc = blockIdx.x & 63;
    const int row0 = bb * 2048 + cc * 32;

    // ---- 1) stage X tile (fp32 -> bf16 LDS) ----
    {
        int r = tid >> 5, c8 = (tid & 31) * 8;
        cvt8(X + (size_t)(row0 + r) * 256 + c8, &Abf[r * 264 + c8]);
    }
    __syncthreads();

    // ---- 2) GEMM1: wave owns cols nb..nb+47 (3 n-frags x 2 m-frags) ----
    const int nb = wid * 48;
    const unsigned short* Wu = (const unsigned short*)Wbk;
    f32x4 acc[2][3] = {};
    for (int k0 = 0; k0 < 256; k0 += 32) {
        s16x8 a[2], b[3];
        #pragma unroll
        for (int mf = 0; mf < 2; ++mf)
            a[mf] = *(const s16x8*)&Abf[(mf * 16 + lrow) * 264 + k0 + lk8];
        #pragma unroll
        for (int nf = 0; nf < 3; ++nf)
            b[nf] = *(const s16x8*)(Wu + (size_t)(nb + nf * 16 + lrow) * 256 + k0 + lk8);
        #pragma unroll
        for (int mf = 0; mf < 2; ++mf)
            #pragma unroll
            for (int nf = 0; nf < 3; ++nf)
                acc[mf][nf] = __builtin_amdgcn_mfma_f32_16x16x32_bf16(
                    a[mf], b[nf], acc[mf][nf], 0, 0, 0);
    }
    __syncthreads();   // all A reads done before Abf region is reused as Vt

    // ---- 3) epilogue -> Hkq / Vt LDS (+ Vb global) ----
    #pragma unroll
    for (int nf = 0; nf < 3; ++nf) {
        int n = nb + nf * 16 + lrow;
        float bias = (n < 256) ? kb1[n] : (n < 512) ? qb1[n - 256] : vb[n - 512];
        #pragma unroll
        for (int mf = 0; mf < 2; ++mf) {
            int tb = mf * 16 + t0;
            if (n < 512) {
                #pragma unroll
                for (int r = 0; r < 4; ++r)
                    Hkq[(tb + r) * 520 + n] = f2bf(tanhf(acc[mf][nf][r] + bias));
            } else {
                int d = n - 512;
                float v0 = acc[mf][nf][0] + bias, v1 = acc[mf][nf][1] + bias;
                float v2 = acc[mf][nf][2] + bias, v3 = acc[mf][nf][3] + bias;
                ushort4 u;
                u.x = f2bf(v0); u.y = f2bf(v1); u.z = f2bf(v2); u.w = f2bf(v3);
                *(ushort4*)&Vt[d * 40 + tb] = u;
                unsigned short* Vg = (unsigned short*)Vb + (size_t)(row0 + tb) * 256 + d;
                Vg[0] = u.x; Vg[256] = u.y; Vg[512] = u.z; Vg[768] = u.w;
            }
        }
    }
    __syncthreads();

    // ---- 4) GEMM2 (waves 0-7): layer-2 + trig ----
    if (wid < 8) {
        const int which = wid >> 2;           // 0=K, 1=Q
        const int q = wid & 3, mf = q >> 1, nf = q & 1;
        const int hoff = which * 256;
        const unsigned short* W2u =
            (const unsigned short*)W2bk + (size_t)(which * 32 + nf * 16 + lrow) * 256;
        f32x4 u = {};
        for (int k0 = 0; k0 < 256; k0 += 32) {
            s16x8 a = *(const s16x8*)&Hkq[(mf * 16 + lrow) * 520 + hoff + k0 + lk8];
            s16x8 b = *(const s16x8*)(W2u + k0 + lk8);
            u = __builtin_amdgcn_mfma_f32_16x16x32_bf16(a, b, u, 0, 0, 0);
        }
        const int outk = nf * 16 + lrow;      // phase index 0..31
        const float bias = (which ? qb2 : kb2)[outk];
        float* dst = which ? QP : KP;
        float cs[4], sn[4];
        #pragma unroll
        for (int r = 0; r < 4; ++r) {
            float ph = tanhf(u[r] + bias) * PI_F;
            float s, c_;
            __sincosf(ph, &s, &c_);
            cs[r] = c_; sn[r] = s;
            int row = mf * 16 + t0 + r;
            dst[(size_t)(row0 + row) * 64 + outk]      = c_;
            dst[(size_t)(row0 + row) * 64 + 32 + outk] = s;
        }
        if (which == 0) {
            ushort4 uc, us;
            uc.x = f2bf(cs[0]); uc.y = f2bf(cs[1]); uc.z = f2bf(cs[2]); uc.w = f2bf(cs[3]);
            us.x = f2bf(sn[0]); us.y = f2bf(sn[1]); us.z = f2bf(sn[2]); us.w = f2bf(sn[3]);
            *(ushort4*)&CKc[outk * 40 + mf * 16 + t0] = uc;
            *(ushort4*)&CKs[outk * 40 + mf * 16 + t0] = us;
        }
    }
    __syncthreads();

    // ---- 5) GEMM3: chunk sums. wave wid owns d-block wid*16..+15 ----
    {
        s16x8 bV = *(const s16x8*)&Vt[(wid * 16 + lrow) * 40 + lk8];
        s16x8 c0 = *(const s16x8*)&CKc[(lrow) * 40 + lk8];
        s16x8 c1 = *(const s16x8*)&CKc[(16 + lrow) * 40 + lk8];
        s16x8 s0 = *(const s16x8*)&CKs[(lrow) * 40 + lk8];
        s16x8 s1 = *(const s16x8*)&CKs[(16 + lrow) * 40 + lk8];
        f32x4 z = {};
        f32x4 r0 = __builtin_amdgcn_mfma_f32_16x16x32_bf16(c0, bV, z, 0, 0, 0);
        f32x4 r1 = __builtin_amdgcn_mfma_f32_16x16x32_bf16(c1, bV, z, 0, 0, 0);
        f32x4 i0 = __builtin_amdgcn_mfma_f32_16x16x32_bf16(s0, bV, z, 0, 0, 0);
        f32x4 i1 = __builtin_amdgcn_mfma_f32_16x16x32_bf16(s1, bV, z, 0, 0, 0);
        const int d = wid * 16 + lrow;
        size_t base = (((size_t)(bb * 64 + cc)) * 32) * 256 + d;
        unsigned short* SRu = (unsigned short*)SRg;
        unsigned short* SIu = (unsigned short*)SIg;
        #pragma unroll
        for (int r = 0; r < 4; ++r) {
            int ka = t0 + r, kb_ = 16 + t0 + r;
            SRu[base + (size_t)ka  * 256] = f2bf(r0[r]);
            SRu[base + (size_t)kb_ * 256] = f2bf(r1[r]);
            SIu[base + (size_t)ka  * 256] = f2bf(i0[r]);
            SIu[base + (size_t)kb_ * 256] = f2bf(i1[r]);
        }
    }
}

// ---------------------------------------------------------------------------
// Kernel C: segment partial sums (4 segs x 16 chunks). grid (128, 2) y=R/I.
// PS layout: [b][seg][8192] fp32.
// ---------------------------------------------------------------------------
__global__ __launch_bounds__(256) void k_scanpart(
    const bf16* __restrict__ SRg, const bf16* __restrict__ SIg,
    float* __restrict__ PSR, float* __restrict__ PSI)
{
    const unsigned short* S = (const unsigned short*)(blockIdx.y ? SIg : SRg);
    float* PS = blockIdx.y ? PSI : PSR;
    int gid = blockIdx.x * 256 + threadIdx.x;     // 0..32767
    int b = gid >> 14, seg = (gid >> 12) & 3, e2 = gid & 4095;
    size_t base = ((size_t)(b * 64 + seg * 16)) * 8192 + e2 * 2;
    float s0 = 0.f, s1 = 0.f;
    #pragma unroll
    for (int c = 0; c < 16; ++c) {
        ushort2 u = *(const ushort2*)(S + base + (size_t)c * 8192);
        s0 += bf2f(u.x); s1 += bf2f(u.y);
    }
    size_t pb = ((size_t)(b * 4 + seg)) * 8192 + e2 * 2;
    PS[pb] = s0; PS[pb + 1] = s1;
}

// ---------------------------------------------------------------------------
// Kernel D: output. grid (128, 4): x = b*64+c, y = d-quarter (64 cols).
// Prefix state rebuilt inline: sum of prior segment PS tiles (fp32) + prior
// chunk-sum tiles within segment (bf16).
// ---------------------------------------------------------------------------
__global__ __launch_bounds__(256) void k_attnout(
    const float* __restrict__ KP, const float* __restrict__ QP,
    const bf16* __restrict__ Vb,
    const bf16* __restrict__ SRg, const bf16* __restrict__ SIg,
    const float* __restrict__ PSR, const float* __restrict__ PSI,
    float* __restrict__ out)
{
    __shared__ float QPc[32 * 68], KPc[32 * 68], Sl[32 * 36];
    __shared__ float vall[32 * 68], PRl[32 * 68], PIl[32 * 68];
    const int tid = threadIdx.x;
    const int b = blockIdx.x >> 6, c = blockIdx.x & 63;
    const int dh = blockIdx.y;
    const int row0 = b * 2048 + c * 32;

    #pragma unroll
    for (int it = 0; it < 2; ++it) {
        int idx = tid + it * 256, t = idx >> 4, j4 = idx & 15;
        *(v4f*)&QPc[t * 68 + j4 * 4] = *(const v4f*)(QP + (size_t)(row0 + t) * 64 + j4 * 4);
        *(v4f*)&KPc[t * 68 + j4 * 4] = *(const v4f*)(KP + (size_t)(row0 + t) * 64 + j4 * 4);
    }
    {   // V slice bf16 -> LDS fp32
        int t = tid >> 3, e8 = (tid & 7) * 8;
        s16x8 u = *(const s16x8*)((const unsigned short*)Vb
                                  + (size_t)(row0 + t) * 256 + dh * 64 + e8);
        #pragma unroll
        for (int j = 0; j < 8; ++j) vall[t * 68 + e8 + j] = bf2f((unsigned short)u[j]);
    }
    {   // inline exclusive-prefix reconstruction
        int k = tid >> 3, dg = tid & 7;
        float pr[8] = {}, pi[8] = {};
        int seg = c >> 4;
        for (int s = 0; s < seg; ++s) {
            size_t pb = ((size_t)(b * 4 + s)) * 8192 + k * 256 + dh * 64 + dg * 8;
            v4f r0 = *(const v4f*)(PSR + pb), r1 = *(const v4f*)(PSR + pb + 4);
            v4f i0 = *(const v4f*)(PSI + pb), i1 = *(const v4f*)(PSI + pb + 4);
            #pragma unroll
            for (int j = 0; j < 4; ++j) {
                pr[j] += r0[j]; pr[4 + j] += r1[j];
                pi[j] += i0[j]; pi[4 + j] += i1[j];
            }
        }
        for (int cp = (seg << 4); cp < c; ++cp) {
            size_t sb = (((size_t)(b * 64 + cp)) * 32 + k) * 256 + dh * 64 + dg * 8;
            s16x8 ur = *(const s16x8*)((const unsigned short*)SRg + sb);
            s16x8 ui = *(const s16x8*)((const unsigned short*)SIg + sb);
            #pragma unroll
            for (int j = 0; j < 8; ++j) {
                pr[j] += bf2f((unsigned short)ur[j]);
                pi[j] += bf2f((unsigned short)ui[j]);
            }
        }
        #pragma unroll
        for (int j = 0; j < 8; ++j) {
            PRl[k * 68 + dg * 8 + j] = pr[j];
            PIl[k * 68 + dg * 8 + j] = pi[j];
        }
    }
    __syncthreads();
    {   // S tile (32x32, causal-masked)
        const int sl = tid >> 3, tq = tid & 7;
        float s4[4] = {0.f, 0.f, 0.f, 0.f};
        for (int j4 = 0; j4 < 16; ++j4) {
            v4f q4 = *(const v4f*)&QPc[sl * 68 + j4 * 4];
            #pragma unroll
            for (int i = 0; i < 4; ++i) {
                v4f k4 = *(const v4f*)&KPc[(tq * 4 + i) * 68 + j4 * 4];
                s4[i] += q4[0]*k4[0] + q4[1]*k4[1] + q4[2]*k4[2] + q4[3]*k4[3];
            }
        }
        #pragma unroll
        for (int i = 0; i < 4; ++i) {
            int t = tq * 4 + i;
            Sl[sl * 36 + t] = (t <= sl) ? s4[i] : 0.f;
        }
    }
    __syncthreads();
    const int l = tid & 31, dq = tid >> 5;
    const int d0 = dq * 8;
    float acc[8] = {};
    for (int k = 0; k < 32; ++k) {
        float qc = QPc[l * 68 + k], qs = QPc[l * 68 + 32 + k];
        #pragma unroll
        for (int j4 = 0; j4 < 2; ++j4) {
            v4f pr = *(const v4f*)&PRl[k * 68 + d0 + j4 * 4];
            v4f pi = *(const v4f*)&PIl[k * 68 + d0 + j4 * 4];
            #pragma unroll
            for (int x = 0; x < 4; ++x)
                acc[j4 * 4 + x] += qc * pr[x] + qs * pi[x];
        }
    }
    for (int t = 0; t < 32; ++t) {
        float s = Sl[l * 36 + t];
        #pragma unroll
        for (int j4 = 0; j4 < 2; ++j4) {
            v4f v4 = *(const v4f*)&vall[t * 68 + d0 + j4 * 4];
            #pragma unroll
            for (int x = 0; x < 4; ++x)
                acc[j4 * 4 + x] = fmaf(s, v4[x], acc[j4 * 4 + x]);
        }
    }
    const int gl = c * 32 + l;
    const float inv = rsqrtf((float)((gl + 1) * 32));
    const size_t ob = ((size_t)(b * 2048 + gl)) * 256 + dh * 64 + d0;
    #pragma unroll
    for (int j4 = 0; j4 < 2; ++j4) {
        v4f v;
        #pragma unroll
        for (int x = 0; x < 4; ++x) v[x] = acc[j4 * 4 + x] * inv;
        *(v4f*)(out + ob + j4 * 4) = v;
    }
}

// ---------------------------------------------------------------------------
extern "C" void kernel_launch(void* const* d_in, const int* in_sizes, int n_in,
                              void* d_out, int out_size, void* d_ws, size_t ws_size,
                              hipStream_t stream)
{
    const float* x   = (const float*)d_in[0];
    const float* kw1 = (const float*)d_in[1];
    const float* kb1 = (const float*)d_in[2];
    const float* kw2 = (const float*)d_in[3];
    const float* kb2 = (const float*)d_in[4];
    const float* qw1 = (const float*)d_in[5];
    const float* qb1 = (const float*)d_in[6];
    const float* qw2 = (const float*)d_in[7];
    const float* qb2 = (const float*)d_in[8];
    const float* vw  = (const float*)d_in[9];
    const float* vb  = (const float*)d_in[10];
    float* out = (float*)d_out;

    char* ws = (char*)d_ws;
    float* KP  = (float*)ws;   ws += (size_t)4096 * 64 * 4;
    float* QP  = (float*)ws;   ws += (size_t)4096 * 64 * 4;
    float* PSR = (float*)ws;   ws += (size_t)65536 * 4;
    float* PSI = (float*)ws;   ws += (size_t)65536 * 4;
    bf16*  Wb  = (bf16*)ws;    ws += (size_t)768 * 256 * 2;
    bf16*  W2b = (bf16*)ws;    ws += (size_t)64 * 256 * 2;
    bf16*  Vb  = (bf16*)ws;    ws += (size_t)4096 * 256 * 2;
    bf16*  SR  = (bf16*)ws;    ws += (size_t)2 * 64 * 32 * 256 * 2;
    bf16*  SI  = (bf16*)ws;    ws += (size_t)2 * 64 * 32 * 256 * 2;

    k_cvtw    <<<104,          256,  0, stream>>>(kw1, qw1, vw, kw2, qw2, Wb, W2b);
    k_fused1  <<<128,          1024, 0, stream>>>(x, Wb, kb1, qb1, vb, W2b, kb2, qb2,
                                                  KP, QP, Vb, SR, SI);
    k_scanpart<<<dim3(128, 2), 256,  0, stream>>>(SR, SI, PSR, PSI);
    k_attnout <<<dim3(128, 4), 256,  0, stream>>>(KP, QP, Vb, SR, SI, PSR, PSI, out);
}